// Round 15
// baseline (46.191 us; speedup 1.0000x reference)
//
#include <hip/hip_runtime.h>
#include <hip/hip_bf16.h>

#define SDIM 2048
#define DDIM 64
#define HNUM 8
#define QBLK 64
#define KVBLK 64
#define NTHR 256
#define NT (SDIM / KVBLK)
#define NEGV -1.0e9f
#define LOG2E 1.44269504088896f
#define FIXMAX 12.0f

// d_ws layout (bytes). CNT first, 128B-aligned images after.
// Partials: splits 0,1 pack as 2xu16 into d_out's fp32 slots; splits >=2 in ws.
#define WS_CNT 0u
#define WS_KH 128u                       // compacted K bf16 swizzled rows, 4 MiB
#define WS_VH (4194304u + 128u)          // compacted V quarter-packed tiles, 4 MiB
#define WS_O2 (8388608u + 128u)          // split-2 normalized partial O bf16, 4 MiB
#define WS_O3 (12582912u + 128u)         // split-3 partial (nsplit=4 only), 4 MiB
#define ML_OFF(nsp) ((nsp) == 4 ? (16777216u + 128u) : (12582912u + 128u))
#define NEED4 17301632u                  // ML(4x128Ki) after O3
#define NEED3 12976256u                  // ML(3x128Ki) after O2   (<= proven 13.2Mi)

typedef __bf16 bf16x8 __attribute__((ext_vector_type(8)));
typedef __bf16 bf16x4 __attribute__((ext_vector_type(4)));
typedef short s16x4 __attribute__((ext_vector_type(4)));
typedef float f32x4 __attribute__((ext_vector_type(4)));
typedef unsigned short u16;
typedef u16 u16x4 __attribute__((ext_vector_type(4)));
typedef u16 u16x8 __attribute__((ext_vector_type(8)));

__device__ __forceinline__ u16 f2bf(float f) {
    unsigned u = __float_as_uint(f);
    u += 0x7FFFu + ((u >> 16) & 1u);
    return (u16)(u >> 16);
}
__device__ __forceinline__ float bf2f(u16 h) {
    return __uint_as_float((unsigned)h << 16);
}

union U8 { u16 u[8]; u16x8 v; bf16x8 b; };

#define GLD16(g, l) __builtin_amdgcn_global_load_lds( \
    (const __attribute__((address_space(1))) unsigned int*)(g), \
    (__attribute__((address_space(3))) unsigned int*)(l), 16, 0, 0)

__device__ __forceinline__ f32x4 mfma16(s16x4 a, s16x4 b, f32x4 c) {
#if __has_builtin(__builtin_amdgcn_mfma_f32_16x16x16bf16_1k)
    return __builtin_amdgcn_mfma_f32_16x16x16bf16_1k(a, b, c, 0, 0, 0);
#else
    asm("v_mfma_f32_16x16x16_bf16 %0, %1, %2, %0" : "+v"(c) : "v"(a), "v"(b));
    return c;
#endif
}

// ---------------- prep: in-block mask scan + gather-compact K,V images ----------------
// K image:  [bh][slot 2048] rows of 128B; (slot,d) at row*128 + ((2d) ^ ((slot&7)<<4))
// V image:  [bh][kt][mt 4][d 64][4 slots of 8B]; slot for kv-group gk = gk ^ ((d>>2)&3)
__global__ __launch_bounds__(NTHR)
void attn_prep(const float* __restrict__ K, const float* __restrict__ V,
               const int* __restrict__ MK, char* __restrict__ ws) {
    __shared__ float sT[64][68];
    __shared__ int win[64];
    __shared__ int wtot[4];
    const int t = threadIdx.x;
    const int kt = blockIdx.x, bh = blockIdx.y;
    const int b = bh >> 3;
    const int kv0 = kt * KVBLK;
    const int ln = t & 63, wvi = t >> 6;

    const int* m = MK + (size_t)b * SDIM;
    int vals[8], cnt = 0;
    #pragma unroll
    for (int e = 0; e < 8; ++e) {
        vals[e] = m[t * 8 + e];
        cnt += (vals[e] != 0);
    }
    int inc = cnt;
    #pragma unroll
    for (int off = 1; off < 64; off <<= 1) {
        int n = __shfl_up(inc, off);
        if (ln >= off) inc += n;
    }
    if (ln == 63) wtot[wvi] = inc;
    if (t < 64) win[t] = 0;   // tail slots gather row 0 (harmless, masked in main)
    __syncthreads();
    int wbase = 0;
    #pragma unroll
    for (int w = 0; w < 4; ++w) if (w < wvi) wbase += wtot[w];
    const int total = wtot[0] + wtot[1] + wtot[2] + wtot[3];
    int pos = wbase + inc - cnt;   // exclusive prefix
    #pragma unroll
    for (int e = 0; e < 8; ++e) {
        if (vals[e]) {
            if (pos >= kv0 && pos < kv0 + KVBLK) win[pos - kv0] = t * 8 + e;
            ++pos;
        }
    }
    if (t == 0 && kt == 0) ((int*)(ws + WS_CNT))[b] = total;
    __syncthreads();
    if (kv0 >= ((total + KVBLK - 1) & ~(KVBLK - 1))) return;   // block-uniform exit

    const size_t base = (size_t)bh * SDIM * DDIM;
    const int r = t >> 2, c16 = (t & 3) * 16;
    const int sw = (r & 7) << 4;
    const int orig = win[r];

    {
        const float* kp = K + base + (size_t)orig * DDIM + c16;
        char* khrow = ws + WS_KH + ((size_t)bh * SDIM + kv0 + r) * 128;
        #pragma unroll
        for (int j = 0; j < 2; ++j) {
            const float4 a = *(const float4*)(kp + 8 * j);
            const float4 c = *(const float4*)(kp + 8 * j + 4);
            float f[8] = {a.x, a.y, a.z, a.w, c.x, c.y, c.z, c.w};
            U8 h;
            #pragma unroll
            for (int e = 0; e < 8; ++e) h.u[e] = f2bf(f[e]);
            *(u16x8*)(khrow + ((2 * c16 + 16 * j) ^ sw)) = h.v;
        }
    }
    {
        const float* vp = V + base + (size_t)orig * DDIM + c16;
        #pragma unroll
        for (int j = 0; j < 4; ++j)
            *(float4*)&sT[r][c16 + 4 * j] = *(const float4*)(vp + 4 * j);
    }
    __syncthreads();
    {
        const int mt = t >> 6, d = t & 63;
        char* dst = ws + WS_VH + ((size_t)(bh * NT + kt)) * 8192 + mt * 2048 + d * 32;
        #pragma unroll
        for (int gk = 0; gk < 4; ++gk) {
            u16x4 h;
            #pragma unroll
            for (int e = 0; e < 4; ++e)
                h[e] = f2bf(sT[mt * 16 + 4 * gk + e][d]);
            *(u16x4*)(dst + (((gk ^ ((d >> 2) & 3)) << 3))) = h;
        }
    }
}

// ---------------- main: R13 loop; runtime nsplit; all partials normalized bf16 -------
__global__ __launch_bounds__(NTHR, 4)
void attn_main(const float* __restrict__ Q, char* __restrict__ ws,
               float* __restrict__ O, int nsplit) {
    __shared__ __align__(16) u16 sK[2][4096];   // 2 x 8KB K tile
    __shared__ __align__(16) u16 sV[2][4096];   // 2 x 8KB V tile (quarter-packed)

    const int tid = threadIdx.x;
    const int wv = tid >> 6, ln = tid & 63;
    const int g = ln >> 4, mi = ln & 15;
    const int bh = blockIdx.y, b = bh >> 3;
    const int split = blockIdx.z;
    const size_t base = (size_t)bh * SDIM * DDIM;
    const int qrow = blockIdx.x * QBLK + 16 * wv + mi;

    const int L = ((const int*)(ws + WS_CNT))[b];
    const int nt = (L + KVBLK - 1) >> 6;
    const int per = (nt + nsplit - 1) / nsplit;
    const int t0 = split * per;
    const int tn = min(nt, t0 + per);

    const int sw = (mi & 7) << 4;
    const int c0 = (16 * g) ^ sw;
    const int c1 = (64 + 16 * g) ^ sw;
    const int vslot = (g ^ (mi >> 2)) << 3;   // byte offset of this lane's 8B V slot

    // ---- Q fragments (hi only), scaled by (1/8)*log2(e); 2 k-slices ----
    bf16x8 qf[2];
    {
        const float* qp = Q + base + (size_t)qrow * DDIM;
        #pragma unroll
        for (int ks = 0; ks < 2; ++ks) {
            const float4 a = *(const float4*)(qp + 32 * ks + 8 * g);
            const float4 c = *(const float4*)(qp + 32 * ks + 8 * g + 4);
            float f[8] = {a.x, a.y, a.z, a.w, c.x, c.y, c.z, c.w};
            U8 h;
            #pragma unroll
            for (int e = 0; e < 8; ++e) h.u[e] = f2bf(f[e] * (0.125f * LOG2E));
            qf[ks] = h.b;
        }
    }

    const char* kgl = ws + WS_KH + (size_t)bh * SDIM * 128;
    const char* vgl = ws + WS_VH + (size_t)bh * NT * 8192;

    f32x4 zero4 = {0.f, 0.f, 0.f, 0.f};
    // fixed softmax max folded into the QK accumulator init: s = K.Q - FIXMAX
    f32x4 minit = {-FIXMAX, -FIXMAX, -FIXMAX, -FIXMAX};
    f32x4 oacc[4];
    #pragma unroll
    for (int i = 0; i < 4; ++i) oacc[i] = zero4;
    float lr0 = 0.f, lr1 = 0.f, lr2 = 0.f, lr3 = 0.f;

    // each wave stages its 2KB quarter of both K and V tiles (4 GLD/wave/tile)
#define STAGE_T(kt_, buf_) do { \
    const char* ksrc_ = kgl + (size_t)(kt_) * 8192 + wv * 2048; \
    char* kdst_ = (char*)&sK[buf_][0] + wv * 2048; \
    GLD16(ksrc_ + ln * 16, kdst_); \
    GLD16(ksrc_ + 1024 + ln * 16, kdst_ + 1024); \
    const char* vsrc_ = vgl + (size_t)(kt_) * 8192 + wv * 2048; \
    char* vdst_ = (char*)&sV[buf_][0] + wv * 2048; \
    GLD16(vsrc_ + ln * 16, vdst_); \
    GLD16(vsrc_ + 1024 + ln * 16, vdst_ + 1024); \
} while (0)

    if (t0 < tn) {
        STAGE_T(t0, 0);
        int cur = 0;
        for (int kt = t0; kt < tn; ++kt) {
            const int kn = (kt + 1 < tn) ? kt + 1 : t0;
            STAGE_T(kn, cur ^ 1);
            // wait current tile's 4 DMA (leave next 4 in flight)
            asm volatile("s_waitcnt vmcnt(4)" ::: "memory");
            __builtin_amdgcn_s_barrier();

            // ---- S^T = K . Q^T - FIXMAX : s[mt] rows kv=16mt+4g+r, cols q=mi ----
            const char* kb = (const char*)&sK[cur][0] + mi * 128;
            f32x4 s[4];
            #pragma unroll
            for (int mt = 0; mt < 4; ++mt) {
                f32x4 acc = minit;
                const bf16x8 a0 = *(const bf16x8*)(kb + mt * 2048 + c0);
                const bf16x8 a1 = *(const bf16x8*)(kb + mt * 2048 + c1);
                acc = __builtin_amdgcn_mfma_f32_16x16x32_bf16(a0, qf[0], acc, 0, 0, 0);
                acc = __builtin_amdgcn_mfma_f32_16x16x32_bf16(a1, qf[1], acc, 0, 0, 0);
                s[mt] = acc;
            }
            // tail masking (wave-uniform fast path)
            const int rem = L - kt * KVBLK;
            if (rem < KVBLK) {
                #pragma unroll
                for (int mt = 0; mt < 4; ++mt)
                    #pragma unroll
                    for (int r = 0; r < 4; ++r)
                        if (16 * mt + 4 * g + r >= rem) s[mt][r] = NEGV;
            }

            // ---- softmax (fixed max folded) -> P in registers (B-frag of mfma16) ----
            bf16x4 pw[4];
            #pragma unroll
            for (int mt = 0; mt < 4; ++mt) {
                float psum = 0.f;
                #pragma unroll
                for (int r = 0; r < 4; ++r) {
                    const float p = __builtin_amdgcn_exp2f(s[mt][r]);
                    pw[mt][r] = (__bf16)p;
                    psum += p;
                }
                if (mt == 0) lr0 += psum;
                else if (mt == 1) lr1 += psum;
                else if (mt == 2) lr2 += psum;
                else lr3 += psum;
            }

            // ---- O^T += V^T . P^T  (16x16x16 per (dt, mt-slice)) ----
            const char* vb = (const char*)&sV[cur][0] + mi * 32 + vslot;
            #pragma unroll
            for (int dt = 0; dt < 4; ++dt) {
                #pragma unroll
                for (int mt = 0; mt < 4; ++mt) {
                    const s16x4 vf = *(const s16x4*)(vb + mt * 2048 + dt * 512);
                    oacc[dt] = mfma16(vf, __builtin_bit_cast(s16x4, pw[mt]), oacc[dt]);
                }
            }
            // all reads of buf cur done -> next iter may overwrite it
            __builtin_amdgcn_s_barrier();
            cur ^= 1;
        }
    }
#undef STAGE_T

    // ---- finalize: normalized bf16 partial per split ----
    float lrun = lr0 + lr1 + lr2 + lr3;
    lrun += __shfl_xor(lrun, 16);
    lrun += __shfl_xor(lrun, 32);
    asm volatile("s_waitcnt vmcnt(0)" ::: "memory");   // drain trailing DMA
    const float inv = lrun > 0.f ? 1.0f / lrun : 0.f;
    u16x4 pb[4];
    #pragma unroll
    for (int dt = 0; dt < 4; ++dt)
        #pragma unroll
        for (int r = 0; r < 4; ++r) pb[dt][r] = f2bf(oacc[dt][r] * inv);

    if (split < 2) {
        // pack into d_out: fp32 slot e holds {lo: split0, hi: split1} u16 partials
        u16* ob = (u16*)(O + base + (size_t)qrow * DDIM) + split;
        #pragma unroll
        for (int dt = 0; dt < 4; ++dt)
            #pragma unroll
            for (int r = 0; r < 4; ++r)
                ob[2 * (16 * dt + 4 * g + r)] = pb[dt][r];
    } else {
        u16* op = (u16*)(ws + (split == 2 ? WS_O2 : WS_O3)) +
                  ((size_t)bh * SDIM + qrow) * DDIM;
        #pragma unroll
        for (int dt = 0; dt < 4; ++dt)
            *(u16x4*)(op + 16 * dt + 4 * g) = pb[dt];
    }
    if (g == 0) {
        float* lp = (float*)(ws + ML_OFF(nsplit)) +
                    ((size_t)(split * 2 * HNUM + bh) * SDIM + qrow);
        *lp = lrun;
    }
}

// ---------------- combine: O = sum_s l_s*P_s / sum_s l_s  (shared fixed max) ---------
__global__ __launch_bounds__(NTHR)
void attn_combine(const char* __restrict__ ws, float* __restrict__ O, int nsplit) {
    const int t = threadIdx.x;
    const size_t grow = (size_t)blockIdx.x * 16 + (t >> 4);
    const int e4 = (t & 15) * 4;
    const float* ml = (const float*)(ws + ML_OFF(nsplit));
    const size_t mstride = (size_t)2 * HNUM * SDIM;
    float l0 = ml[grow];
    float l1 = ml[mstride + grow];
    float l2 = ml[2 * mstride + grow];
    float l3 = (nsplit == 4) ? ml[3 * mstride + grow] : 0.f;
    const float lsum = l0 + l1 + l2 + l3;
    const float inv = lsum > 0.f ? 1.0f / lsum : 0.f;
    l0 *= inv; l1 *= inv; l2 *= inv; l3 *= inv;

    float* op = O + grow * DDIM + e4;
    const float4 o01 = *(const float4*)op;                 // packed split0/1 u16 pairs
    const u16x4 p2 = *(const u16x4*)((const u16*)(ws + WS_O2) + grow * DDIM + e4);
    u16x4 p3 = {0, 0, 0, 0};
    if (nsplit == 4)
        p3 = *(const u16x4*)((const u16*)(ws + WS_O3) + grow * DDIM + e4);

    float4 r;
    #pragma unroll
    for (int j = 0; j < 4; ++j) {
        const unsigned u = __float_as_uint(((const float*)&o01)[j]);
        float acc = bf2f((u16)(u & 0xFFFFu)) * l0 + bf2f((u16)(u >> 16)) * l1;
        acc += bf2f(p2[j]) * l2 + bf2f(p3[j]) * l3;
        ((float*)&r)[j] = acc;
    }
    *(float4*)op = r;
}

extern "C" void kernel_launch(void* const* d_in, const int* in_sizes, int n_in,
                              void* d_out, int out_size, void* d_ws, size_t ws_size,
                              hipStream_t stream) {
    const float* q  = (const float*)d_in[0];
    const float* k  = (const float*)d_in[1];
    const float* v  = (const float*)d_in[2];
    const int*   mk = (const int*)d_in[3];
    float* o = (float*)d_out;
    char* ws = (char*)d_ws;

    const int nsplit = (ws_size >= (size_t)NEED4) ? 4 : 3;   // NEED3 <= proven 13.2Mi

    dim3 pgrid(NT, 2 * HNUM);
    attn_prep<<<pgrid, NTHR, 0, stream>>>(k, v, mk, ws);

    dim3 grid(SDIM / QBLK, 2 * HNUM, nsplit);
    attn_main<<<grid, NTHR, 0, stream>>>(q, ws, o, nsplit);

    dim3 cgrid((2 * HNUM * SDIM) / 16);
    attn_combine<<<cgrid, NTHR, 0, stream>>>(ws, o, nsplit);
}

// Round 16
// 34.963 us; speedup vs baseline: 1.3211x; 1.3211x over previous
//
#include <hip/hip_runtime.h>
#include <hip/hip_bf16.h>

#define SDIM 2048
#define DDIM 64
#define HNUM 8
#define QBLK 128
#define KVBLK 64
#define NTHR 512
#define PTHR 256
#define NT (SDIM / KVBLK)
#define NSPLIT 2
#define NEGV -1.0e9f
#define LOG2E 1.44269504088896f
#define FIXMAX 12.0f

// d_ws layout (bytes), ~13.2 MiB total (same as R13):
#define WS_KH 0u                   // compacted K bf16 swizzled rows, 4 MiB
#define WS_VH 4194304u             // compacted V quarter-packed tiles, 4 MiB
#define WS_O1 8388608u             // split-1 normalized partial O, bf16, 4 MiB
#define WS_ML 12582912u            // l (float) per [split][bh][row], 256 KiB
#define WS_CNT 13123584u           // counts int32 [b], 8 B

typedef __bf16 bf16x8 __attribute__((ext_vector_type(8)));
typedef __bf16 bf16x4 __attribute__((ext_vector_type(4)));
typedef short s16x4 __attribute__((ext_vector_type(4)));
typedef float f32x4 __attribute__((ext_vector_type(4)));
typedef unsigned short u16;
typedef u16 u16x4 __attribute__((ext_vector_type(4)));
typedef u16 u16x8 __attribute__((ext_vector_type(8)));

__device__ __forceinline__ u16 f2bf(float f) {
    unsigned u = __float_as_uint(f);
    u += 0x7FFFu + ((u >> 16) & 1u);
    return (u16)(u >> 16);
}
__device__ __forceinline__ float bf2f(u16 h) {
    return __uint_as_float((unsigned)h << 16);
}

union U8 { u16 u[8]; u16x8 v; bf16x8 b; };

#define GLD16(g, l) __builtin_amdgcn_global_load_lds( \
    (const __attribute__((address_space(1))) unsigned int*)(g), \
    (__attribute__((address_space(3))) unsigned int*)(l), 16, 0, 0)

__device__ __forceinline__ f32x4 mfma16(s16x4 a, s16x4 b, f32x4 c) {
#if __has_builtin(__builtin_amdgcn_mfma_f32_16x16x16bf16_1k)
    return __builtin_amdgcn_mfma_f32_16x16x16bf16_1k(a, b, c, 0, 0, 0);
#else
    asm("v_mfma_f32_16x16x16_bf16 %0, %1, %2, %0" : "+v"(c) : "v"(a), "v"(b));
    return c;
#endif
}

// ---------------- prep: in-block mask scan + gather-compact K,V images (R13) ---------
// K image:  [bh][slot 2048] rows of 128B; (slot,d) at row*128 + ((2d) ^ ((slot&7)<<4))
// V image:  [bh][kt][mt 4][d 64][4 slots of 8B]; slot for kv-group gk = gk ^ ((d>>2)&3)
__global__ __launch_bounds__(PTHR)
void attn_prep(const float* __restrict__ K, const float* __restrict__ V,
               const int* __restrict__ MK, char* __restrict__ ws) {
    __shared__ float sT[64][68];
    __shared__ int win[64];
    __shared__ int wtot[4];
    const int t = threadIdx.x;
    const int kt = blockIdx.x, bh = blockIdx.y;
    const int b = bh >> 3;
    const int kv0 = kt * KVBLK;
    const int ln = t & 63, wvi = t >> 6;

    const int* m = MK + (size_t)b * SDIM;
    int vals[8], cnt = 0;
    #pragma unroll
    for (int e = 0; e < 8; ++e) {
        vals[e] = m[t * 8 + e];
        cnt += (vals[e] != 0);
    }
    int inc = cnt;
    #pragma unroll
    for (int off = 1; off < 64; off <<= 1) {
        int n = __shfl_up(inc, off);
        if (ln >= off) inc += n;
    }
    if (ln == 63) wtot[wvi] = inc;
    if (t < 64) win[t] = 0;   // tail slots gather row 0 (harmless, masked in main)
    __syncthreads();
    int wbase = 0;
    #pragma unroll
    for (int w = 0; w < 4; ++w) if (w < wvi) wbase += wtot[w];
    const int total = wtot[0] + wtot[1] + wtot[2] + wtot[3];
    int pos = wbase + inc - cnt;   // exclusive prefix
    #pragma unroll
    for (int e = 0; e < 8; ++e) {
        if (vals[e]) {
            if (pos >= kv0 && pos < kv0 + KVBLK) win[pos - kv0] = t * 8 + e;
            ++pos;
        }
    }
    if (t == 0 && kt == 0) ((int*)(ws + WS_CNT))[b] = total;
    __syncthreads();
    if (kv0 >= ((total + KVBLK - 1) & ~(KVBLK - 1))) return;   // block-uniform exit

    const size_t base = (size_t)bh * SDIM * DDIM;
    const int r = t >> 2, c16 = (t & 3) * 16;
    const int sw = (r & 7) << 4;
    const int orig = win[r];

    {
        const float* kp = K + base + (size_t)orig * DDIM + c16;
        char* khrow = ws + WS_KH + ((size_t)bh * SDIM + kv0 + r) * 128;
        #pragma unroll
        for (int j = 0; j < 2; ++j) {
            const float4 a = *(const float4*)(kp + 8 * j);
            const float4 c = *(const float4*)(kp + 8 * j + 4);
            float f[8] = {a.x, a.y, a.z, a.w, c.x, c.y, c.z, c.w};
            U8 h;
            #pragma unroll
            for (int e = 0; e < 8; ++e) h.u[e] = f2bf(f[e]);
            *(u16x8*)(khrow + ((2 * c16 + 16 * j) ^ sw)) = h.v;
        }
    }
    {
        const float* vp = V + base + (size_t)orig * DDIM + c16;
        #pragma unroll
        for (int j = 0; j < 4; ++j)
            *(float4*)&sT[r][c16 + 4 * j] = *(const float4*)(vp + 4 * j);
    }
    __syncthreads();
    {
        const int mt = t >> 6, d = t & 63;
        char* dst = ws + WS_VH + ((size_t)(bh * NT + kt)) * 8192 + mt * 2048 + d * 32;
        #pragma unroll
        for (int gk = 0; gk < 4; ++gk) {
            u16x4 h;
            #pragma unroll
            for (int e = 0; e < 4; ++e)
                h[e] = f2bf(sT[mt * 16 + 4 * gk + e][d]);
            *(u16x4*)(dst + (((gk ^ ((d >> 2) & 3)) << 3))) = h;
        }
    }
}

// ---------------- main: R13 inner loop; 8 waves share each staged tile ---------------
__global__ __launch_bounds__(NTHR, 4)
void attn_main(const float* __restrict__ Q, char* __restrict__ ws,
               float* __restrict__ O) {
    __shared__ __align__(16) u16 sK[2][4096];   // 2 x 8KB K tile
    __shared__ __align__(16) u16 sV[2][4096];   // 2 x 8KB V tile (quarter-packed)

    const int tid = threadIdx.x;
    const int wv = tid >> 6, ln = tid & 63;     // wv in 0..7
    const int g = ln >> 4, mi = ln & 15;
    const int bh = blockIdx.y, b = bh >> 3;
    const int split = blockIdx.z;
    const size_t base = (size_t)bh * SDIM * DDIM;
    const int qrow = blockIdx.x * QBLK + 16 * wv + mi;   // 8 waves x 16 rows = 128

    const int L = ((const int*)(ws + WS_CNT))[b];
    const int nt = (L + KVBLK - 1) >> 6;
    const int half = (nt + 1) >> 1;
    const int t0 = split ? half : 0;
    const int tn = split ? nt : half;

    const int sw = (mi & 7) << 4;
    const int c0 = (16 * g) ^ sw;
    const int c1 = (64 + 16 * g) ^ sw;
    const int vslot = (g ^ (mi >> 2)) << 3;   // byte offset of this lane's 8B V slot

    // ---- Q fragments (hi only), scaled by (1/8)*log2(e); 2 k-slices ----
    bf16x8 qf[2];
    {
        const float* qp = Q + base + (size_t)qrow * DDIM;
        #pragma unroll
        for (int ks = 0; ks < 2; ++ks) {
            const float4 a = *(const float4*)(qp + 32 * ks + 8 * g);
            const float4 c = *(const float4*)(qp + 32 * ks + 8 * g + 4);
            float f[8] = {a.x, a.y, a.z, a.w, c.x, c.y, c.z, c.w};
            U8 h;
            #pragma unroll
            for (int e = 0; e < 8; ++e) h.u[e] = f2bf(f[e] * (0.125f * LOG2E));
            qf[ks] = h.b;
        }
    }

    const char* kgl = ws + WS_KH + (size_t)bh * SDIM * 128;
    const char* vgl = ws + WS_VH + (size_t)bh * NT * 8192;

    f32x4 zero4 = {0.f, 0.f, 0.f, 0.f};
    // fixed softmax max folded into the QK accumulator init: s = K.Q - FIXMAX
    f32x4 minit = {-FIXMAX, -FIXMAX, -FIXMAX, -FIXMAX};
    f32x4 oacc[4];
    #pragma unroll
    for (int i = 0; i < 4; ++i) oacc[i] = zero4;
    float lr0 = 0.f, lr1 = 0.f, lr2 = 0.f, lr3 = 0.f;

    // each of the 8 waves stages its 1KB of K and 1KB of V (2 GLD/wave/tile)
#define STAGE_T(kt_, buf_) do { \
    GLD16(kgl + (size_t)(kt_) * 8192 + wv * 1024 + ln * 16, \
          (char*)&sK[buf_][0] + wv * 1024); \
    GLD16(vgl + (size_t)(kt_) * 8192 + wv * 1024 + ln * 16, \
          (char*)&sV[buf_][0] + wv * 1024); \
} while (0)

    if (t0 < tn) {
        STAGE_T(t0, 0);
        int cur = 0;
        for (int kt = t0; kt < tn; ++kt) {
            const int kn = (kt + 1 < tn) ? kt + 1 : t0;
            STAGE_T(kn, cur ^ 1);
            // wait current tile's 2 DMA (leave next 2 in flight)
            asm volatile("s_waitcnt vmcnt(2)" ::: "memory");
            __builtin_amdgcn_s_barrier();

            // ---- S^T = K . Q^T - FIXMAX : s[mt] rows kv=16mt+4g+r, cols q=mi ----
            const char* kb = (const char*)&sK[cur][0] + mi * 128;
            f32x4 s[4];
            #pragma unroll
            for (int mt = 0; mt < 4; ++mt) {
                f32x4 acc = minit;
                const bf16x8 a0 = *(const bf16x8*)(kb + mt * 2048 + c0);
                const bf16x8 a1 = *(const bf16x8*)(kb + mt * 2048 + c1);
                acc = __builtin_amdgcn_mfma_f32_16x16x32_bf16(a0, qf[0], acc, 0, 0, 0);
                acc = __builtin_amdgcn_mfma_f32_16x16x32_bf16(a1, qf[1], acc, 0, 0, 0);
                s[mt] = acc;
            }
            // tail masking (wave-uniform fast path)
            const int rem = L - kt * KVBLK;
            if (rem < KVBLK) {
                #pragma unroll
                for (int mt = 0; mt < 4; ++mt)
                    #pragma unroll
                    for (int r = 0; r < 4; ++r)
                        if (16 * mt + 4 * g + r >= rem) s[mt][r] = NEGV;
            }

            // ---- softmax (fixed max folded) -> P in registers (B-frag of mfma16) ----
            bf16x4 pw[4];
            #pragma unroll
            for (int mt = 0; mt < 4; ++mt) {
                float psum = 0.f;
                #pragma unroll
                for (int r = 0; r < 4; ++r) {
                    const float p = __builtin_amdgcn_exp2f(s[mt][r]);
                    pw[mt][r] = (__bf16)p;
                    psum += p;
                }
                if (mt == 0) lr0 += psum;
                else if (mt == 1) lr1 += psum;
                else if (mt == 2) lr2 += psum;
                else lr3 += psum;
            }

            // ---- O^T += V^T . P^T  (16x16x16 per (dt, mt-slice)) ----
            const char* vb = (const char*)&sV[cur][0] + mi * 32 + vslot;
            #pragma unroll
            for (int dt = 0; dt < 4; ++dt) {
                #pragma unroll
                for (int mt = 0; mt < 4; ++mt) {
                    const s16x4 vf = *(const s16x4*)(vb + mt * 2048 + dt * 512);
                    oacc[dt] = mfma16(vf, __builtin_bit_cast(s16x4, pw[mt]), oacc[dt]);
                }
            }
            // all reads of buf cur done -> next iter may overwrite it
            __builtin_amdgcn_s_barrier();
            cur ^= 1;
        }
    }
#undef STAGE_T

    // ---- finalize: per-wave rows, reduce l across kv lane-groups ----
    float lrun = lr0 + lr1 + lr2 + lr3;
    lrun += __shfl_xor(lrun, 16);
    lrun += __shfl_xor(lrun, 32);
    asm volatile("s_waitcnt vmcnt(0)" ::: "memory");   // drain trailing DMA
    const float inv = lrun > 0.f ? 1.0f / lrun : 0.f;
    if (split == 0) {
        float* op = O + base + (size_t)qrow * DDIM;
        #pragma unroll
        for (int dt = 0; dt < 4; ++dt) {
            float4 o;
            o.x = oacc[dt][0] * inv;
            o.y = oacc[dt][1] * inv;
            o.z = oacc[dt][2] * inv;
            o.w = oacc[dt][3] * inv;
            *(float4*)(op + 16 * dt + 4 * g) = o;
        }
    } else {
        u16* op1 = (u16*)(ws + WS_O1) + ((size_t)bh * SDIM + qrow) * DDIM;
        #pragma unroll
        for (int dt = 0; dt < 4; ++dt) {
            u16x4 o;
            #pragma unroll
            for (int r = 0; r < 4; ++r) o[r] = f2bf(oacc[dt][r] * inv);
            *(u16x4*)(op1 + 16 * dt + 4 * g) = o;
        }
    }
    if (g == 0) {
        float* lp = (float*)(ws + WS_ML) + ((size_t)(split * 2 * HNUM + bh) * SDIM + qrow);
        *lp = lrun;
    }
}

// ---------------- combine: O = (l0*O0 + l1*O1) / (l0+l1)  (shared fixed max) --------
__global__ __launch_bounds__(PTHR)
void attn_combine(const char* __restrict__ ws, float* __restrict__ O) {
    const int t = threadIdx.x;
    const size_t grow = (size_t)blockIdx.x * 16 + (t >> 4);
    const int e4 = (t & 15) * 4;
    const float* ml = (const float*)(ws + WS_ML);
    float w0 = ml[grow];
    float w1 = ml[(size_t)2 * HNUM * SDIM + grow];
    const float swt = w0 + w1;
    const float inv = swt > 0.f ? 1.0f / swt : 0.f;
    w0 *= inv; w1 *= inv;
    float* op = O + grow * DDIM + e4;
    const float4 o0 = *(const float4*)op;
    const u16x4 o1 = *(const u16x4*)((const u16*)(ws + WS_O1) + grow * DDIM + e4);
    float4 r;
    r.x = o0.x * w0 + bf2f(o1[0]) * w1;
    r.y = o0.y * w0 + bf2f(o1[1]) * w1;
    r.z = o0.z * w0 + bf2f(o1[2]) * w1;
    r.w = o0.w * w0 + bf2f(o1[3]) * w1;
    *(float4*)op = r;
}

extern "C" void kernel_launch(void* const* d_in, const int* in_sizes, int n_in,
                              void* d_out, int out_size, void* d_ws, size_t ws_size,
                              hipStream_t stream) {
    const float* q  = (const float*)d_in[0];
    const float* k  = (const float*)d_in[1];
    const float* v  = (const float*)d_in[2];
    const int*   mk = (const int*)d_in[3];
    float* o = (float*)d_out;
    char* ws = (char*)d_ws;   // needs ~13.2 MiB

    dim3 pgrid(NT, 2 * HNUM);
    attn_prep<<<pgrid, PTHR, 0, stream>>>(k, v, mk, ws);

    dim3 grid(SDIM / QBLK, 2 * HNUM, NSPLIT);
    attn_main<<<grid, NTHR, 0, stream>>>(q, ws, o);

    dim3 cgrid((2 * HNUM * SDIM) / 16);
    attn_combine<<<cgrid, PTHR, 0, stream>>>(ws, o);
}

// Round 17
// 34.692 us; speedup vs baseline: 1.3315x; 1.0078x over previous
//
#include <hip/hip_runtime.h>
#include <hip/hip_bf16.h>

#define SDIM 2048
#define DDIM 64
#define HNUM 8
#define QBLK 256
#define KVBLK 64
#define NTHR 1024
#define PTHR 256
#define NT (SDIM / KVBLK)
#define NSPLIT 2
#define NEGV -1.0e9f
#define LOG2E 1.44269504088896f
#define FIXMAX 12.0f

// d_ws layout (bytes), ~13.2 MiB total (same as R13/R16):
#define WS_KH 0u                   // compacted K bf16 swizzled rows, 4 MiB
#define WS_VH 4194304u             // compacted V quarter-packed tiles, 4 MiB
#define WS_O1 8388608u             // split-1 normalized partial O, bf16, 4 MiB
#define WS_ML 12582912u            // l (float) per [split][bh][row], 256 KiB
#define WS_CNT 13123584u           // counts int32 [b], 8 B

typedef __bf16 bf16x8 __attribute__((ext_vector_type(8)));
typedef __bf16 bf16x4 __attribute__((ext_vector_type(4)));
typedef short s16x4 __attribute__((ext_vector_type(4)));
typedef float f32x4 __attribute__((ext_vector_type(4)));
typedef unsigned short u16;
typedef u16 u16x4 __attribute__((ext_vector_type(4)));
typedef u16 u16x8 __attribute__((ext_vector_type(8)));

__device__ __forceinline__ u16 f2bf(float f) {
    unsigned u = __float_as_uint(f);
    u += 0x7FFFu + ((u >> 16) & 1u);
    return (u16)(u >> 16);
}
__device__ __forceinline__ float bf2f(u16 h) {
    return __uint_as_float((unsigned)h << 16);
}

union U8 { u16 u[8]; u16x8 v; bf16x8 b; };

#define GLD16(g, l) __builtin_amdgcn_global_load_lds( \
    (const __attribute__((address_space(1))) unsigned int*)(g), \
    (__attribute__((address_space(3))) unsigned int*)(l), 16, 0, 0)

__device__ __forceinline__ f32x4 mfma16(s16x4 a, s16x4 b, f32x4 c) {
#if __has_builtin(__builtin_amdgcn_mfma_f32_16x16x16bf16_1k)
    return __builtin_amdgcn_mfma_f32_16x16x16bf16_1k(a, b, c, 0, 0, 0);
#else
    asm("v_mfma_f32_16x16x16_bf16 %0, %1, %2, %0" : "+v"(c) : "v"(a), "v"(b));
    return c;
#endif
}

// ---------------- prep: in-block mask scan + gather-compact K,V images (R13) ---------
// K image:  [bh][slot 2048] rows of 128B; (slot,d) at row*128 + ((2d) ^ ((slot&7)<<4))
// V image:  [bh][kt][mt 4][d 64][4 slots of 8B]; slot for kv-group gk = gk ^ ((d>>2)&3)
__global__ __launch_bounds__(PTHR)
void attn_prep(const float* __restrict__ K, const float* __restrict__ V,
               const int* __restrict__ MK, char* __restrict__ ws) {
    __shared__ float sT[64][68];
    __shared__ int win[64];
    __shared__ int wtot[4];
    const int t = threadIdx.x;
    const int kt = blockIdx.x, bh = blockIdx.y;
    const int b = bh >> 3;
    const int kv0 = kt * KVBLK;
    const int ln = t & 63, wvi = t >> 6;

    const int* m = MK + (size_t)b * SDIM;
    int vals[8], cnt = 0;
    #pragma unroll
    for (int e = 0; e < 8; ++e) {
        vals[e] = m[t * 8 + e];
        cnt += (vals[e] != 0);
    }
    int inc = cnt;
    #pragma unroll
    for (int off = 1; off < 64; off <<= 1) {
        int n = __shfl_up(inc, off);
        if (ln >= off) inc += n;
    }
    if (ln == 63) wtot[wvi] = inc;
    if (t < 64) win[t] = 0;   // tail slots gather row 0 (harmless, masked in main)
    __syncthreads();
    int wbase = 0;
    #pragma unroll
    for (int w = 0; w < 4; ++w) if (w < wvi) wbase += wtot[w];
    const int total = wtot[0] + wtot[1] + wtot[2] + wtot[3];
    int pos = wbase + inc - cnt;   // exclusive prefix
    #pragma unroll
    for (int e = 0; e < 8; ++e) {
        if (vals[e]) {
            if (pos >= kv0 && pos < kv0 + KVBLK) win[pos - kv0] = t * 8 + e;
            ++pos;
        }
    }
    if (t == 0 && kt == 0) ((int*)(ws + WS_CNT))[b] = total;
    __syncthreads();
    if (kv0 >= ((total + KVBLK - 1) & ~(KVBLK - 1))) return;   // block-uniform exit

    const size_t base = (size_t)bh * SDIM * DDIM;
    const int r = t >> 2, c16 = (t & 3) * 16;
    const int sw = (r & 7) << 4;
    const int orig = win[r];

    {
        const float* kp = K + base + (size_t)orig * DDIM + c16;
        char* khrow = ws + WS_KH + ((size_t)bh * SDIM + kv0 + r) * 128;
        #pragma unroll
        for (int j = 0; j < 2; ++j) {
            const float4 a = *(const float4*)(kp + 8 * j);
            const float4 c = *(const float4*)(kp + 8 * j + 4);
            float f[8] = {a.x, a.y, a.z, a.w, c.x, c.y, c.z, c.w};
            U8 h;
            #pragma unroll
            for (int e = 0; e < 8; ++e) h.u[e] = f2bf(f[e]);
            *(u16x8*)(khrow + ((2 * c16 + 16 * j) ^ sw)) = h.v;
        }
    }
    {
        const float* vp = V + base + (size_t)orig * DDIM + c16;
        #pragma unroll
        for (int j = 0; j < 4; ++j)
            *(float4*)&sT[r][c16 + 4 * j] = *(const float4*)(vp + 4 * j);
    }
    __syncthreads();
    {
        const int mt = t >> 6, d = t & 63;
        char* dst = ws + WS_VH + ((size_t)(bh * NT + kt)) * 8192 + mt * 2048 + d * 32;
        #pragma unroll
        for (int gk = 0; gk < 4; ++gk) {
            u16x4 h;
            #pragma unroll
            for (int e = 0; e < 4; ++e)
                h[e] = f2bf(sT[mt * 16 + 4 * gk + e][d]);
            *(u16x4*)(dst + (((gk ^ ((d >> 2) & 3)) << 3))) = h;
        }
    }
}

// ---------------- main: R16 inner loop; 16 waves share each staged tile --------------
__global__ __launch_bounds__(NTHR, 4)
void attn_main(const float* __restrict__ Q, char* __restrict__ ws,
               float* __restrict__ O) {
    __shared__ __align__(16) u16 sK[2][4096];   // 2 x 8KB K tile
    __shared__ __align__(16) u16 sV[2][4096];   // 2 x 8KB V tile (quarter-packed)

    const int tid = threadIdx.x;
    const int wv = tid >> 6, ln = tid & 63;     // wv in 0..15
    const int g = ln >> 4, mi = ln & 15;
    const int bh = blockIdx.y, b = bh >> 3;
    const int split = blockIdx.z;
    const size_t base = (size_t)bh * SDIM * DDIM;
    const int qrow = blockIdx.x * QBLK + 16 * wv + mi;   // 16 waves x 16 rows = 256

    const int L = ((const int*)(ws + WS_CNT))[b];
    const int nt = (L + KVBLK - 1) >> 6;
    const int half = (nt + 1) >> 1;
    const int t0 = split ? half : 0;
    const int tn = split ? nt : half;

    const int sw = (mi & 7) << 4;
    const int c0 = (16 * g) ^ sw;
    const int c1 = (64 + 16 * g) ^ sw;
    const int vslot = (g ^ (mi >> 2)) << 3;   // byte offset of this lane's 8B V slot

    // ---- Q fragments (hi only), scaled by (1/8)*log2(e); 2 k-slices ----
    bf16x8 qf[2];
    {
        const float* qp = Q + base + (size_t)qrow * DDIM;
        #pragma unroll
        for (int ks = 0; ks < 2; ++ks) {
            const float4 a = *(const float4*)(qp + 32 * ks + 8 * g);
            const float4 c = *(const float4*)(qp + 32 * ks + 8 * g + 4);
            float f[8] = {a.x, a.y, a.z, a.w, c.x, c.y, c.z, c.w};
            U8 h;
            #pragma unroll
            for (int e = 0; e < 8; ++e) h.u[e] = f2bf(f[e] * (0.125f * LOG2E));
            qf[ks] = h.b;
        }
    }

    const char* kgl = ws + WS_KH + (size_t)bh * SDIM * 128;
    const char* vgl = ws + WS_VH + (size_t)bh * NT * 8192;

    f32x4 zero4 = {0.f, 0.f, 0.f, 0.f};
    // fixed softmax max folded into the QK accumulator init: s = K.Q - FIXMAX
    f32x4 minit = {-FIXMAX, -FIXMAX, -FIXMAX, -FIXMAX};
    f32x4 oacc[4];
    #pragma unroll
    for (int i = 0; i < 4; ++i) oacc[i] = zero4;
    float lr0 = 0.f, lr1 = 0.f, lr2 = 0.f, lr3 = 0.f;

    // 16 waves, 16KB/tile: each wave stages exactly one 1KB chunk (K: wv<8, V: wv>=8)
    const int sch = (wv & 7) * 1024;
#define STAGE_T(kt_, buf_) do { \
    if (wv < 8) { \
        GLD16(kgl + (size_t)(kt_) * 8192 + sch + ln * 16, \
              (char*)&sK[buf_][0] + sch); \
    } else { \
        GLD16(vgl + (size_t)(kt_) * 8192 + sch + ln * 16, \
              (char*)&sV[buf_][0] + sch); \
    } \
} while (0)

    if (t0 < tn) {
        STAGE_T(t0, 0);
        int cur = 0;
        for (int kt = t0; kt < tn; ++kt) {
            const int kn = (kt + 1 < tn) ? kt + 1 : t0;
            STAGE_T(kn, cur ^ 1);
            // wait current tile's 1 DMA (leave next tile's 1 in flight)
            asm volatile("s_waitcnt vmcnt(1)" ::: "memory");
            __builtin_amdgcn_s_barrier();

            // ---- S^T = K . Q^T - FIXMAX : s[mt] rows kv=16mt+4g+r, cols q=mi ----
            const char* kb = (const char*)&sK[cur][0] + mi * 128;
            f32x4 s[4];
            #pragma unroll
            for (int mt = 0; mt < 4; ++mt) {
                f32x4 acc = minit;
                const bf16x8 a0 = *(const bf16x8*)(kb + mt * 2048 + c0);
                const bf16x8 a1 = *(const bf16x8*)(kb + mt * 2048 + c1);
                acc = __builtin_amdgcn_mfma_f32_16x16x32_bf16(a0, qf[0], acc, 0, 0, 0);
                acc = __builtin_amdgcn_mfma_f32_16x16x32_bf16(a1, qf[1], acc, 0, 0, 0);
                s[mt] = acc;
            }
            // tail masking (wave-uniform fast path)
            const int rem = L - kt * KVBLK;
            if (rem < KVBLK) {
                #pragma unroll
                for (int mt = 0; mt < 4; ++mt)
                    #pragma unroll
                    for (int r = 0; r < 4; ++r)
                        if (16 * mt + 4 * g + r >= rem) s[mt][r] = NEGV;
            }

            // ---- softmax (fixed max folded) -> P in registers (B-frag of mfma16) ----
            bf16x4 pw[4];
            #pragma unroll
            for (int mt = 0; mt < 4; ++mt) {
                float psum = 0.f;
                #pragma unroll
                for (int r = 0; r < 4; ++r) {
                    const float p = __builtin_amdgcn_exp2f(s[mt][r]);
                    pw[mt][r] = (__bf16)p;
                    psum += p;
                }
                if (mt == 0) lr0 += psum;
                else if (mt == 1) lr1 += psum;
                else if (mt == 2) lr2 += psum;
                else lr3 += psum;
            }

            // ---- O^T += V^T . P^T  (16x16x16 per (dt, mt-slice)) ----
            const char* vb = (const char*)&sV[cur][0] + mi * 32 + vslot;
            #pragma unroll
            for (int dt = 0; dt < 4; ++dt) {
                #pragma unroll
                for (int mt = 0; mt < 4; ++mt) {
                    const s16x4 vf = *(const s16x4*)(vb + mt * 2048 + dt * 512);
                    oacc[dt] = mfma16(vf, __builtin_bit_cast(s16x4, pw[mt]), oacc[dt]);
                }
            }
            // all reads of buf cur done -> next iter may overwrite it
            __builtin_amdgcn_s_barrier();
            cur ^= 1;
        }
    }
#undef STAGE_T

    // ---- finalize: per-wave rows, reduce l across kv lane-groups ----
    float lrun = lr0 + lr1 + lr2 + lr3;
    lrun += __shfl_xor(lrun, 16);
    lrun += __shfl_xor(lrun, 32);
    asm volatile("s_waitcnt vmcnt(0)" ::: "memory");   // drain trailing DMA
    const float inv = lrun > 0.f ? 1.0f / lrun : 0.f;
    if (split == 0) {
        float* op = O + base + (size_t)qrow * DDIM;
        #pragma unroll
        for (int dt = 0; dt < 4; ++dt) {
            float4 o;
            o.x = oacc[dt][0] * inv;
            o.y = oacc[dt][1] * inv;
            o.z = oacc[dt][2] * inv;
            o.w = oacc[dt][3] * inv;
            *(float4*)(op + 16 * dt + 4 * g) = o;
        }
    } else {
        u16* op1 = (u16*)(ws + WS_O1) + ((size_t)bh * SDIM + qrow) * DDIM;
        #pragma unroll
        for (int dt = 0; dt < 4; ++dt) {
            u16x4 o;
            #pragma unroll
            for (int r = 0; r < 4; ++r) o[r] = f2bf(oacc[dt][r] * inv);
            *(u16x4*)(op1 + 16 * dt + 4 * g) = o;
        }
    }
    if (g == 0) {
        float* lp = (float*)(ws + WS_ML) + ((size_t)(split * 2 * HNUM + bh) * SDIM + qrow);
        *lp = lrun;
    }
}

// ---------------- combine: O = (l0*O0 + l1*O1) / (l0+l1)  (shared fixed max) --------
__global__ __launch_bounds__(PTHR)
void attn_combine(const char* __restrict__ ws, float* __restrict__ O) {
    const int t = threadIdx.x;
    const size_t grow = (size_t)blockIdx.x * 16 + (t >> 4);
    const int e4 = (t & 15) * 4;
    const float* ml = (const float*)(ws + WS_ML);
    float w0 = ml[grow];
    float w1 = ml[(size_t)2 * HNUM * SDIM + grow];
    const float swt = w0 + w1;
    const float inv = swt > 0.f ? 1.0f / swt : 0.f;
    w0 *= inv; w1 *= inv;
    float* op = O + grow * DDIM + e4;
    const float4 o0 = *(const float4*)op;
    const u16x4 o1 = *(const u16x4*)((const u16*)(ws + WS_O1) + grow * DDIM + e4);
    float4 r;
    r.x = o0.x * w0 + bf2f(o1[0]) * w1;
    r.y = o0.y * w0 + bf2f(o1[1]) * w1;
    r.z = o0.z * w0 + bf2f(o1[2]) * w1;
    r.w = o0.w * w0 + bf2f(o1[3]) * w1;
    *(float4*)op = r;
}

extern "C" void kernel_launch(void* const* d_in, const int* in_sizes, int n_in,
                              void* d_out, int out_size, void* d_ws, size_t ws_size,
                              hipStream_t stream) {
    const float* q  = (const float*)d_in[0];
    const float* k  = (const float*)d_in[1];
    const float* v  = (const float*)d_in[2];
    const int*   mk = (const int*)d_in[3];
    float* o = (float*)d_out;
    char* ws = (char*)d_ws;   // needs ~13.2 MiB

    dim3 pgrid(NT, 2 * HNUM);
    attn_prep<<<pgrid, PTHR, 0, stream>>>(k, v, mk, ws);

    dim3 grid(SDIM / QBLK, 2 * HNUM, NSPLIT);
    attn_main<<<grid, NTHR, 0, stream>>>(q, ws, o);

    dim3 cgrid((2 * HNUM * SDIM) / 16);
    attn_combine<<<cgrid, PTHR, 0, stream>>>(ws, o);
}